// Round 5
// baseline (152.355 us; speedup 1.0000x reference)
//
#include <hip/hip_runtime.h>
#include <math.h>

#define BB 4
#define CC 64
#define HH_ 128
#define WW 128
#define HPW (HH_*WW)     // 16384
#define KH 64
#define KW 64
#define KSZ 7
#define AA 16
#define EPSV 1e-5f
#define KTOT 448         // KSZ*CC... K = k*64+ci

typedef __attribute__((ext_vector_type(8))) short bf16x8;
typedef __attribute__((ext_vector_type(4))) float f32x4;
typedef unsigned short ushort_t;

__device__ __forceinline__ float sigm(float x){ return 1.0f/(1.0f+expf(-x)); }
__device__ __forceinline__ unsigned short f2bf(float f){
  unsigned u = __float_as_uint(f);
  return (unsigned short)((u + 0x7fffu + ((u>>16)&1u)) >> 16);
}

// attn ws layout: sc1[4][64] @0, sf1 @256, sc2 @512, sf2 @768, ssp[4][9] @1024

// ---------------- K0: prep (weight reformat, bf16 convert, gbuf zero) ----------------
__global__ void k_prep(const float* __restrict__ dsw, const float* __restrict__ offw,
                       ushort_t* __restrict__ dsWbf, ushort_t* __restrict__ offAbf,
                       float* __restrict__ gbuf){
  int idx = blockIdx.x*256 + threadIdx.x;
  if(blockIdx.x==0) gbuf[threadIdx.x] = 0.f;
  if(idx < CC*KTOT){
    // dsWbf[co*448 + k*64 + ci] = bf16(dsw[(co*64+ci)*7 + k])
    int co = idx/KTOT; int K = idx%KTOT; int k = K>>6; int ci = K&63;
    dsWbf[idx] = f2bf(dsw[(size_t)(co*CC+ci)*KSZ + k]);
  } else {
    int j2 = idx - CC*KTOT;
    if(j2 < 18*16*32){
      // offAbf[(s*16+co)*32+kl]: s=(tap,chalf), ci=chalf*32+kl; co>=7 -> 0
      int kl = j2&31; int co = (j2>>5)&15; int s = j2>>9;
      int tap = s>>1; int ci = (s&1)*32 + kl;
      float v = 0.f;
      if(co<KSZ) v = offw[((size_t)co*CC + ci)*9 + tap];
      offAbf[j2] = f2bf(v);
    }
  }
}

// ---------------- K2a: attention scalars (1 block, LDS-staged) ----------------
__global__ __launch_bounds__(256) void k_att1(const float* __restrict__ g,
  const float* __restrict__ o1fc, const float* __restrict__ o1g,const float* __restrict__ o1b,
  const float* __restrict__ o1m,const float* __restrict__ o1v,
  const float* __restrict__ o1cw,const float* __restrict__ o1cb,
  const float* __restrict__ o1fw,const float* __restrict__ o1fb,
  const float* __restrict__ o2fc, const float* __restrict__ o2g,const float* __restrict__ o2b,
  const float* __restrict__ o2m,const float* __restrict__ o2v,
  const float* __restrict__ o2cw,const float* __restrict__ o2cb,
  const float* __restrict__ o2fw,const float* __restrict__ o2fb,
  const float* __restrict__ spw,const float* __restrict__ spb,
  float* __restrict__ attn)
{
  __shared__ float sg[BB*CC], sfc1[AA*CC], sfc2[AA*CC];
  __shared__ float scw1[CC*AA], sfw1[CC*AA], scw2[CC*AA], sfw2[CC*AA];
  __shared__ float sa1[BB][AA], sa2[BB][AA];
  int t = threadIdx.x;
  sg[t] = g[t] * (1.0f/HPW);
  for(int i=t;i<AA*CC;i+=256){
    sfc1[i]=o1fc[i]; sfc2[i]=o2fc[i];
    scw1[i]=o1cw[i]; sfw1[i]=o1fw[i];
    scw2[i]=o2cw[i]; sfw2[i]=o2fw[i];
  }
  __syncthreads();
  if(t < BB*AA){
    int b=t>>4, j=t&15;
    float v1=0.f, v2=0.f;
    for(int c=0;c<CC;c++){ float gv = sg[b*CC+c]; v1 += gv*sfc1[j*CC+c]; v2 += gv*sfc2[j*CC+c]; }
    v1 = (v1-o1m[j])*rsqrtf(o1v[j]+EPSV)*o1g[j]+o1b[j]; sa1[b][j]=fmaxf(v1,0.f);
    v2 = (v2-o2m[j])*rsqrtf(o2v[j]+EPSV)*o2g[j]+o2b[j]; sa2[b][j]=fmaxf(v2,0.f);
  }
  __syncthreads();
  { int b=t>>6, c=t&63;
    float d1=o1cb[c], d2=o1fb[c], d3=o2cb[c], d4=o2fb[c];
    #pragma unroll
    for(int j=0;j<AA;j++){
      float a1=sa1[b][j], a2=sa2[b][j];
      d1+=a1*scw1[c*AA+j]; d2+=a1*sfw1[c*AA+j];
      d3+=a2*scw2[c*AA+j]; d4+=a2*sfw2[c*AA+j];
    }
    attn[      t]=sigm(d1); attn[256+ t]=sigm(d2);
    attn[512+  t]=sigm(d3); attn[768+ t]=sigm(d4);
  }
  if(t < BB*9){
    int b=t/9,k=t%9; float d=spb[k];
    #pragma unroll
    for(int j=0;j<AA;j++) d+=sa2[b][j]*spw[k*AA+j];
    attn[1024+t]=sigm(d);
  }
}

// ---------------- K2b: weff, grid (b,o), 64 thr = ci ----------------
__global__ __launch_bounds__(64) void k_weff(const float* __restrict__ w,
  const float* __restrict__ attn, const float* __restrict__ ratio_p,
  float* __restrict__ weff)
{
  int bo = blockIdx.x; int b = bo>>6, o = bo&63; int ci = threadIdx.x;
  const float* wp = w + (size_t)(o*CC+ci)*9;
  float w9[9]; float m=0.f;
  #pragma unroll
  for(int e=0;e<9;e++){ w9[e]=wp[e]; m+=w9[e]; }
  m *= (1.0f/9.0f);
  float S1 = m * attn[b*CC+ci];           // sc1
  float c2v = attn[512 + b*CC+ci];        // sc2
  float M[9];
  #pragma unroll
  for(int e=0;e<9;e++) M[e] = (w9[e]-m)*c2v;
  #pragma unroll
  for(int off=32; off>0; off>>=1){
    S1 += __shfl_xor(S1, off);
    #pragma unroll
    for(int e=0;e<9;e++) M[e] += __shfl_xor(M[e], off);
  }
  if(ci==0){
    const float Dm[3][3] = {{2.f,2.f,2.f},{1.7320508075688772f,0.f,-1.7320508075688772f},{1.f,-2.f,1.f}};
    const float Di[3][3] = {{0.16666666666666666f,0.28867513459481287f,0.16666666666666666f},
                            {0.16666666666666666f,0.f,-0.3333333333333333f},
                            {0.16666666666666666f,-0.28867513459481287f,0.16666666666666666f}};
    float U[3][3], T[3][3], V[3][3], R[3][3];
    for(int k=0;k<3;k++)for(int n=0;n<3;n++) U[k][n]=Dm[k][0]*M[0*3+n]+Dm[k][1]*M[1*3+n]+Dm[k][2]*M[2*3+n];
    for(int k=0;k<3;k++)for(int l=0;l<3;l++) T[k][l]=(U[k][0]*Dm[l][0]+U[k][1]*Dm[l][1]+U[k][2]*Dm[l][2])*2.0f*attn[1024+b*9+k*3+l];
    for(int k=0;k<3;k++)for(int n=0;n<3;n++) V[k][n]=Di[k][0]*T[0][n]+Di[k][1]*T[1][n]+Di[k][2]*T[2][n];
    for(int k=0;k<3;k++)for(int l=0;l<3;l++) R[k][l]=V[k][0]*Di[l][0]+V[k][1]*Di[l][1]+V[k][2]*Di[l][2];
    float rr = ratio_p[0];
    float base = rr*4.0f*attn[256+b*CC+o]*S1;        // sf1
    float w2f = (1.0f-rr)*4.0f*attn[768+b*CC+o];     // sf2
    #pragma unroll
    for(int e=0;e<9;e++) weff[(size_t)bo*9+e] = base + w2f*R[e/3][e%3];
  }
}

// ---------------- K3a: HH from x + fused mean (atomic partials) ----------------
__global__ void k_dwt_hh(const float* __restrict__ x, float* __restrict__ HHb,
                         float* __restrict__ gbuf){
  int idx = blockIdx.x*256 + threadIdx.x;   // BB*CC*KH*KW = 1048576
  int w = idx & 63; int h = (idx>>6)&63; int bc = idx>>12;
  const float* xp = x + (size_t)bc*HPW;
  float2 r0 = *(const float2*)(xp + (2*h)*WW + 2*w);
  float2 r1 = *(const float2*)(xp + (2*h+1)*WW + 2*w);
  HHb[idx] = 0.5f*(r0.x - r1.x - r0.y + r1.y);
  float s = r0.x + r0.y + r1.x + r1.y;
  for(int o=32;o>0;o>>=1) s += __shfl_down(s,o);
  __shared__ float ls[4];
  int t = threadIdx.x;
  if((t&63)==0) ls[t>>6]=s;
  __syncthreads();
  if(t==0) atomicAdd(&gbuf[bc], ls[0]+ls[1]+ls[2]+ls[3]);
}

// ---------------- K3b: out = 2x + iwt(0,0,0, conv(HH)-HH) ----------------
__global__ void k_iwt(const float* __restrict__ HHb, const float* __restrict__ x,
                      const float* __restrict__ weff, float* __restrict__ outb){
  int bc = blockIdx.x;
  float wk[9];
  #pragma unroll
  for(int e=0;e<9;e++) wk[e] = weff[(size_t)bc*9+e];
  const float* Hp = HHb + (size_t)bc*KH*KW;
  const float* xp = x + (size_t)bc*HPW;
  float* op = outb + (size_t)bc*HPW;
  for(int idx=threadIdx.x; idx<KH*KW; idx+=256){
    int h = idx>>6, w = idx&63;
    float acc = 0.f;
    #pragma unroll
    for(int dh=-1;dh<=1;dh++){ int hh=h+dh; if(hh<0||hh>=KH) continue;
      #pragma unroll
      for(int dw=-1;dw<=1;dw++){ int ww=w+dw; if(ww<0||ww>=KW) continue;
        acc += wk[(dh+1)*3+(dw+1)] * Hp[hh*KW+ww]; } }
    float d = 0.5f*(acc - Hp[idx]);
    float2 xr0 = *(const float2*)(xp + (2*h)*WW + 2*w);
    float2 xr1 = *(const float2*)(xp + (2*h+1)*WW + 2*w);
    float2 o0, o1;
    o0.x = 2.f*xr0.x + d;  o0.y = 2.f*xr0.y - d;
    o1.x = 2.f*xr1.x - d;  o1.y = 2.f*xr1.y + d;
    *(float2*)(op + (2*h)*WW + 2*w) = o0;
    *(float2*)(op + (2*h+1)*WW + 2*w) = o1;
  }
}

// ---------------- K3c: transpose NCHW out -> outT[b,h,w,c] ----------------
__global__ void k_transpose(const float* __restrict__ outb, float* __restrict__ outT){
  int b = blockIdx.x >> 7; int h = blockIdx.x & 127;
  __shared__ float tile[CC][WW+1];
  int t = threadIdx.x;
  for(int e=t; e<CC*WW; e+=256){ int c=e>>7, w=e&127; tile[c][w] = outb[((size_t)(b*CC+c)*HH_+h)*WW + w]; }
  __syncthreads();
  float* dst = outT + ((size_t)(b*HH_+h))*WW*CC;
  for(int e=t; e<CC*WW; e+=256){ int w=e>>6, c=e&63; dst[e] = tile[c][w]; }
}

// ---------------- K4: offset conv as bf16 MFMA + BN + tanh + cumsum -> dy ----------------
// block (h, b): C[7co x 128w] = W[7 x 576] * patch[576 x 128], K=(tap9, ci64)
__global__ __launch_bounds__(256) void k_off(const float* __restrict__ outT,
  const ushort_t* __restrict__ offAbf, const float* __restrict__ offb,
  const float* __restrict__ obg, const float* __restrict__ obb,
  const float* __restrict__ obm, const float* __restrict__ obv,
  float* __restrict__ dyb)
{
  __shared__ ushort_t SB[3*130*64];    // 49920 B, XOR-swizzled
  __shared__ float off_s[KSZ*128];
  int t = threadIdx.x;
  int h = blockIdx.x, b = blockIdx.y;
  int wid = t>>6, lane = t&63;
  // stage rows h-1..h+1, zero-padded (SAME conv)
  for(int e=wid; e<390; e+=4){
    int r = e/130, wp = e - r*130;
    int hr = h - 1 + r;
    float v = 0.f;
    if(hr>=0 && hr<HH_ && wp>=1 && wp<=128)
      v = outT[(((size_t)(b*HH_+hr))*WW + (wp-1))*CC + lane];
    int idx = (r*130+wp)*64 + lane;
    SB[idx ^ ((wp&7)<<3)] = f2bf(v);
  }
  __syncthreads();
  int arow = lane&15, kgrp = lane>>4;
  f32x4 acc[2]; acc[0]=(f32x4){0.f,0.f,0.f,0.f}; acc[1]=(f32x4){0.f,0.f,0.f,0.f};
  #pragma unroll
  for(int s=0;s<18;s++){
    int tap = s>>1, chalf = s&1;
    bf16x8 aF = *(const bf16x8*)(offAbf + (s*16+arow)*32 + kgrp*8);
    int r = tap/3, dwp = tap%3;
    #pragma unroll
    for(int n2=0;n2<2;n2++){
      int w = (wid*2+n2)*16 + arow;
      int wp = w + dwp;
      int off = (((r*130+wp)*64) + chalf*32 + kgrp*8)*2 ^ ((wp&7)<<4);
      bf16x8 bF = *(const bf16x8*)((const char*)SB + off);
      acc[n2] = __builtin_amdgcn_mfma_f32_16x16x32_bf16(aF, bF, acc[n2], 0,0,0);
    }
  }
  #pragma unroll
  for(int n2=0;n2<2;n2++){
    #pragma unroll
    for(int r=0;r<4;r++){
      int co = kgrp*4+r;
      if(co<KSZ) off_s[co*128 + (wid*2+n2)*16 + arow] = acc[n2][r];
    }
  }
  __syncthreads();
  if(t<128){
    int w = t;
    float y[KSZ];
    #pragma unroll
    for(int k=0;k<KSZ;k++){
      float sc = obg[k]*rsqrtf(obv[k]+EPSV);
      float sh = obb[k]-obm[k]*sc;
      y[k] = tanhf((off_s[k*128+w]+offb[k])*sc+sh);
    }
    float d0=y[0]+y[1]+y[2], d1=y[1]+y[2], d2=y[2];
    float d4=y[4], d5=y[4]+y[5], d6=y[4]+y[5]+y[6];
    size_t base = ((size_t)b*KSZ)*HPW + h*WW + w;
    dyb[base]=d0; dyb[base+HPW]=d1; dyb[base+2*HPW]=d2; dyb[base+3*HPW]=0.f;
    dyb[base+4*HPW]=d4; dyb[base+5*HPW]=d5; dyb[base+6*HPW]=d6;
  }
}

// ---------------- K5: deform sample + 7x1 conv as bf16 MFMA GEMM (+GN partials) ----------------
__global__ __launch_bounds__(256) void k_dsconv(const float* __restrict__ outT,
  const float* __restrict__ dyb, const ushort_t* __restrict__ dsWbf,
  const float* __restrict__ dsb, float* __restrict__ yout, float* __restrict__ pstats)
{
  __shared__ ushort_t S[64*KTOT];      // 57344 B
  __shared__ int sb0[KTOT], sb1[KTOT]; // sample row bases
  __shared__ float swr[KTOT];
  int t = threadIdx.x;
  int wseg = blockIdx.x, h = blockIdx.y, b = blockIdx.z;
  #pragma unroll
  for(int i=0;i<2;i++){
    int e = t + i*256;
    if(e<KTOT){
      int k = e>>6, pz = e&63; int w = wseg*64+pz;
      float dv = dyb[((size_t)(b*KSZ+k)*HH_ + h)*WW + w];
      float r = fminf(fmaxf((float)h + dv, 0.f), 127.f);
      float rf = floorf(r); int r0 = (int)rf; float wr = r - rf; int r1 = min(r0+1,127);
      int c = min(max(w + k - 3,0),127);
      sb0[e] = ((b*HH_ + r0)*WW + c)*CC;
      sb1[e] = ((b*HH_ + r1)*WW + c)*CC;
      swr[e] = wr;
    }
  }
  int wid = t>>6, lane = t&63;
  int arow = lane&15, kgrp = lane>>4;
  bf16x8 aF[14];
  const ushort_t* Wp = dsWbf + (size_t)((wid<<4)+arow)*KTOT + kgrp*8;
  #pragma unroll
  for(int ks=0;ks<14;ks++) aF[ks] = *(const bf16x8*)(Wp + ks*32);
  __syncthreads();
  for(int e=wid; e<KTOT; e+=4){
    int b0 = sb0[e], b1 = sb1[e]; float wr = swr[e];
    float a = outT[b0 + lane];
    float bb = outT[b1 + lane];
    float v = a + wr*(bb-a);
    int pz = e&63; int k = e>>6;
    int idx = pz*KTOT + (k<<6) + lane;      // short index
    S[idx ^ ((pz&7)<<3)] = f2bf(v);         // byte ^= (pz&7)<<4
  }
  __syncthreads();
  f32x4 acc[4];
  #pragma unroll
  for(int nt=0;nt<4;nt++) acc[nt] = (f32x4){0.f,0.f,0.f,0.f};
  #pragma unroll
  for(int nt=0;nt<4;nt++){
    int posb = nt*16 + arow;
    #pragma unroll
    for(int ks=0;ks<14;ks++){
      int off = (posb*(KTOT*2) + ks*64 + kgrp*16) ^ ((posb&7)<<4);
      bf16x8 bF = *(const bf16x8*)((const char*)S + off);
      acc[nt] = __builtin_amdgcn_mfma_f32_16x16x32_bf16(aF[ks], bF, acc[nt], 0,0,0);
    }
  }
  float vs[4]={0.f,0.f,0.f,0.f}, vq[4]={0.f,0.f,0.f,0.f};
  #pragma unroll
  for(int r=0;r<4;r++){
    int co = (wid<<4) + kgrp*4 + r;
    float bias = dsb[co];
    #pragma unroll
    for(int nt=0;nt<4;nt++){
      float y = acc[nt][r] + bias;
      int wcol = wseg*64 + nt*16 + arow;
      yout[((size_t)(b*CC+co)*HH_ + h)*WW + wcol] = y;
      vs[r] += y; vq[r] += y*y;
    }
  }
  #pragma unroll
  for(int m=1;m<16;m<<=1){
    #pragma unroll
    for(int r=0;r<4;r++){ vs[r]+=__shfl_xor(vs[r],m); vq[r]+=__shfl_xor(vq[r],m); }
  }
  if(arow==0){
    #pragma unroll
    for(int r=0;r<4;r++){
      int co = (wid<<4)+kgrp*4+r;
      int pi = (b*CC+co)*256 + h*2 + wseg;
      pstats[pi] = vs[r];
      pstats[65536+pi] = vq[r];
    }
  }
}

// ---------------- K6: reduce GN partials -> group stats ----------------
__global__ __launch_bounds__(256) void k_gnfin2(const float* __restrict__ pstats,
                                                float* __restrict__ gstat){
  int bg = blockIdx.x; int b = bg>>4, g = bg&15; int t = threadIdx.x;
  float s=0.f, q=0.f;
  #pragma unroll
  for(int c4=0;c4<4;c4++){
    int base = (b*CC + g*4+c4)*256;
    s += pstats[base + t];
    q += pstats[65536 + base + t];
  }
  for(int o=32;o>0;o>>=1){ s+=__shfl_down(s,o); q+=__shfl_down(q,o); }
  __shared__ float ls[4], lq[4];
  if((t&63)==0){ ls[t>>6]=s; lq[t>>6]=q; }
  __syncthreads();
  if(t==0){
    float S=ls[0]+ls[1]+ls[2]+ls[3], Q=lq[0]+lq[1]+lq[2]+lq[3];
    float inv = 1.0f/(4.0f*HPW);
    float mu = S*inv; float var = Q*inv - mu*mu;
    gstat[bg*2]=mu; gstat[bg*2+1]=rsqrtf(var+EPSV);
  }
}

// ---------------- K7: apply GN + affine + relu in place ----------------
__global__ void k_gnapply(float* __restrict__ y, const float* __restrict__ gstat,
  const float* __restrict__ gg, const float* __restrict__ gb){
  int idx = blockIdx.x*256 + threadIdx.x;   // float4 index
  float4* p = (float4*)y;
  int bc = idx >> 12;
  int b = bc>>6, c = bc&63;
  int gi = b*16 + (c>>2);
  float mu = gstat[gi*2], rstd = gstat[gi*2+1];
  float sc = rstd*gg[c], sh = gb[c]-mu*sc;
  float4 v = p[idx];
  v.x = fmaxf(v.x*sc+sh, 0.f);
  v.y = fmaxf(v.y*sc+sh, 0.f);
  v.z = fmaxf(v.z*sc+sh, 0.f);
  v.w = fmaxf(v.w*sc+sh, 0.f);
  p[idx] = v;
}

extern "C" void kernel_launch(void* const* d_in, const int* in_sizes, int n_in,
                              void* d_out, int out_size, void* d_ws, size_t ws_size,
                              hipStream_t stream) {
  const float* x      = (const float*)d_in[0];
  const float* weight = (const float*)d_in[1];
  const float* ratio  = (const float*)d_in[2];
  const float* o1fc   = (const float*)d_in[3];
  const float* o1g    = (const float*)d_in[4];
  const float* o1b    = (const float*)d_in[5];
  const float* o1m    = (const float*)d_in[6];
  const float* o1v    = (const float*)d_in[7];
  const float* o1cw   = (const float*)d_in[8];
  const float* o1cb   = (const float*)d_in[9];
  const float* o1fw   = (const float*)d_in[10];
  const float* o1fb   = (const float*)d_in[11];
  const float* o2fc   = (const float*)d_in[12];
  const float* o2g    = (const float*)d_in[13];
  const float* o2b    = (const float*)d_in[14];
  const float* o2m    = (const float*)d_in[15];
  const float* o2v    = (const float*)d_in[16];
  const float* o2cw   = (const float*)d_in[17];
  const float* o2cb   = (const float*)d_in[18];
  const float* o2fw   = (const float*)d_in[19];
  const float* o2fb   = (const float*)d_in[20];
  const float* spw    = (const float*)d_in[21];
  const float* spb    = (const float*)d_in[22];
  const float* offw   = (const float*)d_in[23];
  const float* offb   = (const float*)d_in[24];
  const float* obg    = (const float*)d_in[25];
  const float* obb    = (const float*)d_in[26];
  const float* obm    = (const float*)d_in[27];
  const float* obv    = (const float*)d_in[28];
  const float* dsw    = (const float*)d_in[29];
  const float* dsb    = (const float*)d_in[30];
  const float* gng    = (const float*)d_in[31];
  const float* gnb    = (const float*)d_in[32];

  float* ws    = (float*)d_ws;
  float* outT  = ws;                           // 4194304
  float* HHb   = ws + 4194304;                 // 1048576
  float* dyb   = ws + 5242880;                 // 458752 -> ends 5701632
  float* gbuf  = ws + 5701632;                 // 256
  float* weff  = ws + 5701888;                 // 2304 -> ends 5704192
  ushort_t* dsWbf  = (ushort_t*)(ws + 5704192); // 28672 shorts (14336 f)
  ushort_t* offAbf = (ushort_t*)(ws + 5718528); // 9216 shorts (4608 f)
  float* gstat = ws + 5723136;                 // 128
  float* attn  = ws + 5723264;                 // 1060 -> ends 5724324
  float* pstats= ws + 5724416;                 // 131072 -> ends 5855488
  float* outb  = (float*)d_out;                // NCHW scratch: out -> y -> final

  k_prep<<<148,256,0,stream>>>(dsw, offw, dsWbf, offAbf, gbuf);
  k_dwt_hh<<<4096,256,0,stream>>>(x, HHb, gbuf);
  k_att1<<<1,256,0,stream>>>(gbuf,
    o1fc,o1g,o1b,o1m,o1v,o1cw,o1cb,o1fw,o1fb,
    o2fc,o2g,o2b,o2m,o2v,o2cw,o2cb,o2fw,o2fb,
    spw,spb, attn);
  k_weff<<<256,64,0,stream>>>(weight, attn, ratio, weff);
  k_iwt<<<256,256,0,stream>>>(HHb, x, weff, outb);
  k_transpose<<<512,256,0,stream>>>(outb, outT);
  k_off<<<dim3(128,4),256,0,stream>>>(outT, offAbf, offb, obg, obb, obm, obv, dyb);
  k_dsconv<<<dim3(2,128,4),256,0,stream>>>(outT, dyb, dsWbf, dsb, outb, pstats);
  k_gnfin2<<<64,256,0,stream>>>(pstats, gstat);
  k_gnapply<<<4096,256,0,stream>>>(outb, gstat, gng, gnb);
}

// Round 6
// 113.874 us; speedup vs baseline: 1.3379x; 1.3379x over previous
//
#include <hip/hip_runtime.h>
#include <math.h>

#define BB 4
#define CC 64
#define HH_ 128
#define WW 128
#define HPW (HH_*WW)     // 16384
#define KH 64
#define KW 64
#define KSZ 7
#define AA 16
#define EPSV 1e-5f
#define KTOT 448         // 7*64

typedef __attribute__((ext_vector_type(8))) short bf16x8;
typedef __attribute__((ext_vector_type(4))) float f32x4;
typedef unsigned short ushort_t;

__device__ __forceinline__ float sigm(float x){ return 1.0f/(1.0f+expf(-x)); }
__device__ __forceinline__ unsigned short f2bf(float f){
  unsigned u = __float_as_uint(f);
  return (unsigned short)((u + 0x7fffu + ((u>>16)&1u)) >> 16);
}

// ---------------- K0: prep (weight reformat, bf16 convert, gbuf zero) ----------------
__global__ void k_prep(const float* __restrict__ dsw, const float* __restrict__ offw,
                       ushort_t* __restrict__ dsWbf, ushort_t* __restrict__ offAbf,
                       float* __restrict__ gbuf){
  int idx = blockIdx.x*256 + threadIdx.x;
  if(blockIdx.x==0) gbuf[threadIdx.x] = 0.f;
  if(idx < CC*KTOT){
    int co = idx/KTOT; int K = idx%KTOT; int k = K>>6; int ci = K&63;
    dsWbf[idx] = f2bf(dsw[(size_t)(co*CC+ci)*KSZ + k]);
  } else {
    int j2 = idx - CC*KTOT;
    if(j2 < 18*16*32){
      int kl = j2&31; int co = (j2>>5)&15; int s = j2>>9;
      int tap = s>>1; int ci = (s&1)*32 + kl;
      float v = 0.f;
      if(co<KSZ) v = offw[((size_t)co*CC + ci)*9 + tap];
      offAbf[j2] = f2bf(v);
    }
  }
}

// ---------------- K2a: attention scalars (1 block, LDS-staged) ----------------
__global__ __launch_bounds__(256) void k_att1(const float* __restrict__ g,
  const float* __restrict__ o1fc, const float* __restrict__ o1g,const float* __restrict__ o1b,
  const float* __restrict__ o1m,const float* __restrict__ o1v,
  const float* __restrict__ o1cw,const float* __restrict__ o1cb,
  const float* __restrict__ o1fw,const float* __restrict__ o1fb,
  const float* __restrict__ o2fc, const float* __restrict__ o2g,const float* __restrict__ o2b,
  const float* __restrict__ o2m,const float* __restrict__ o2v,
  const float* __restrict__ o2cw,const float* __restrict__ o2cb,
  const float* __restrict__ o2fw,const float* __restrict__ o2fb,
  const float* __restrict__ spw,const float* __restrict__ spb,
  float* __restrict__ attn)
{
  __shared__ float sg[BB*CC], sfc1[AA*CC], sfc2[AA*CC];
  __shared__ float scw1[CC*AA], sfw1[CC*AA], scw2[CC*AA], sfw2[CC*AA];
  __shared__ float sa1[BB][AA], sa2[BB][AA];
  int t = threadIdx.x;
  sg[t] = g[t] * (1.0f/HPW);
  for(int i=t;i<AA*CC;i+=256){
    sfc1[i]=o1fc[i]; sfc2[i]=o2fc[i];
    scw1[i]=o1cw[i]; sfw1[i]=o1fw[i];
    scw2[i]=o2cw[i]; sfw2[i]=o2fw[i];
  }
  __syncthreads();
  if(t < BB*AA){
    int b=t>>4, j=t&15;
    float v1=0.f, v2=0.f;
    for(int c=0;c<CC;c++){ float gv = sg[b*CC+c]; v1 += gv*sfc1[j*CC+c]; v2 += gv*sfc2[j*CC+c]; }
    v1 = (v1-o1m[j])*rsqrtf(o1v[j]+EPSV)*o1g[j]+o1b[j]; sa1[b][j]=fmaxf(v1,0.f);
    v2 = (v2-o2m[j])*rsqrtf(o2v[j]+EPSV)*o2g[j]+o2b[j]; sa2[b][j]=fmaxf(v2,0.f);
  }
  __syncthreads();
  { int b=t>>6, c=t&63;
    float d1=o1cb[c], d2=o1fb[c], d3=o2cb[c], d4=o2fb[c];
    #pragma unroll
    for(int j=0;j<AA;j++){
      float a1=sa1[b][j], a2=sa2[b][j];
      d1+=a1*scw1[c*AA+j]; d2+=a1*sfw1[c*AA+j];
      d3+=a2*scw2[c*AA+j]; d4+=a2*sfw2[c*AA+j];
    }
    attn[      t]=sigm(d1); attn[256+ t]=sigm(d2);
    attn[512+  t]=sigm(d3); attn[768+ t]=sigm(d4);
  }
  if(t < BB*9){
    int b=t/9,k=t%9; float d=spb[k];
    #pragma unroll
    for(int j=0;j<AA;j++) d+=sa2[b][j]*spw[k*AA+j];
    attn[1024+t]=sigm(d);
  }
}

// ---------------- K2b: weff, grid (b,o), 64 thr = ci ----------------
__global__ __launch_bounds__(64) void k_weff(const float* __restrict__ w,
  const float* __restrict__ attn, const float* __restrict__ ratio_p,
  float* __restrict__ weff)
{
  int bo = blockIdx.x; int b = bo>>6, o = bo&63; int ci = threadIdx.x;
  const float* wp = w + (size_t)(o*CC+ci)*9;
  float w9[9]; float m=0.f;
  #pragma unroll
  for(int e=0;e<9;e++){ w9[e]=wp[e]; m+=w9[e]; }
  m *= (1.0f/9.0f);
  float S1 = m * attn[b*CC+ci];
  float c2v = attn[512 + b*CC+ci];
  float M[9];
  #pragma unroll
  for(int e=0;e<9;e++) M[e] = (w9[e]-m)*c2v;
  #pragma unroll
  for(int off=32; off>0; off>>=1){
    S1 += __shfl_xor(S1, off);
    #pragma unroll
    for(int e=0;e<9;e++) M[e] += __shfl_xor(M[e], off);
  }
  if(ci==0){
    const float Dm[3][3] = {{2.f,2.f,2.f},{1.7320508075688772f,0.f,-1.7320508075688772f},{1.f,-2.f,1.f}};
    const float Di[3][3] = {{0.16666666666666666f,0.28867513459481287f,0.16666666666666666f},
                            {0.16666666666666666f,0.f,-0.3333333333333333f},
                            {0.16666666666666666f,-0.28867513459481287f,0.16666666666666666f}};
    float U[3][3], T[3][3], V[3][3], R[3][3];
    for(int k=0;k<3;k++)for(int n=0;n<3;n++) U[k][n]=Dm[k][0]*M[0*3+n]+Dm[k][1]*M[1*3+n]+Dm[k][2]*M[2*3+n];
    for(int k=0;k<3;k++)for(int l=0;l<3;l++) T[k][l]=(U[k][0]*Dm[l][0]+U[k][1]*Dm[l][1]+U[k][2]*Dm[l][2])*2.0f*attn[1024+b*9+k*3+l];
    for(int k=0;k<3;k++)for(int n=0;n<3;n++) V[k][n]=Di[k][0]*T[0][n]+Di[k][1]*T[1][n]+Di[k][2]*T[2][n];
    for(int k=0;k<3;k++)for(int l=0;l<3;l++) R[k][l]=V[k][0]*Di[l][0]+V[k][1]*Di[l][1]+V[k][2]*Di[l][2];
    float rr = ratio_p[0];
    float base = rr*4.0f*attn[256+b*CC+o]*S1;
    float w2f = (1.0f-rr)*4.0f*attn[768+b*CC+o];
    #pragma unroll
    for(int e=0;e<9;e++) weff[(size_t)bo*9+e] = base + w2f*R[e/3][e%3];
  }
}

// ---------------- K3a: HH from x + fused mean (atomic partials) ----------------
__global__ void k_dwt_hh(const float* __restrict__ x, float* __restrict__ HHb,
                         float* __restrict__ gbuf){
  int idx = blockIdx.x*256 + threadIdx.x;
  int w = idx & 63; int h = (idx>>6)&63; int bc = idx>>12;
  const float* xp = x + (size_t)bc*HPW;
  float2 r0 = *(const float2*)(xp + (2*h)*WW + 2*w);
  float2 r1 = *(const float2*)(xp + (2*h+1)*WW + 2*w);
  HHb[idx] = 0.5f*(r0.x - r1.x - r0.y + r1.y);
  float s = r0.x + r0.y + r1.x + r1.y;
  for(int o=32;o>0;o>>=1) s += __shfl_down(s,o);
  __shared__ float ls[4];
  int t = threadIdx.x;
  if((t&63)==0) ls[t>>6]=s;
  __syncthreads();
  if(t==0) atomicAdd(&gbuf[bc], ls[0]+ls[1]+ls[2]+ls[3]);
}

// ---------------- K3b: out = 2x + iwt(0,0,0, conv(HH)-HH) ----------------
__global__ void k_iwt(const float* __restrict__ HHb, const float* __restrict__ x,
                      const float* __restrict__ weff, float* __restrict__ outb){
  int bc = blockIdx.x;
  float wk[9];
  #pragma unroll
  for(int e=0;e<9;e++) wk[e] = weff[(size_t)bc*9+e];
  const float* Hp = HHb + (size_t)bc*KH*KW;
  const float* xp = x + (size_t)bc*HPW;
  float* op = outb + (size_t)bc*HPW;
  for(int idx=threadIdx.x; idx<KH*KW; idx+=256){
    int h = idx>>6, w = idx&63;
    float acc = 0.f;
    #pragma unroll
    for(int dh=-1;dh<=1;dh++){ int hh=h+dh; if(hh<0||hh>=KH) continue;
      #pragma unroll
      for(int dw=-1;dw<=1;dw++){ int ww=w+dw; if(ww<0||ww>=KW) continue;
        acc += wk[(dh+1)*3+(dw+1)] * Hp[hh*KW+ww]; } }
    float d = 0.5f*(acc - Hp[idx]);
    float2 xr0 = *(const float2*)(xp + (2*h)*WW + 2*w);
    float2 xr1 = *(const float2*)(xp + (2*h+1)*WW + 2*w);
    float2 o0, o1;
    o0.x = 2.f*xr0.x + d;  o0.y = 2.f*xr0.y - d;
    o1.x = 2.f*xr1.x - d;  o1.y = 2.f*xr1.y + d;
    *(float2*)(op + (2*h)*WW + 2*w) = o0;
    *(float2*)(op + (2*h+1)*WW + 2*w) = o1;
  }
}

// ---------------- K3c: transpose -> outT[b,h,w,c] f32 + outTbf[b,h,130,c] bf16 padded ----------------
__global__ void k_transpose(const float* __restrict__ outb, float* __restrict__ outT,
                            ushort_t* __restrict__ outTbf){
  int b = blockIdx.x >> 7; int h = blockIdx.x & 127;
  __shared__ float tile[CC][WW+1];
  int t = threadIdx.x;
  for(int e=t; e<CC*WW; e+=256){ int c=e>>7, w=e&127; tile[c][w] = outb[((size_t)(b*CC+c)*HH_+h)*WW + w]; }
  __syncthreads();
  float* dst = outT + ((size_t)(b*HH_+h))*WW*CC;
  ushort_t* dstb = outTbf + ((size_t)(b*HH_+h))*130*CC;
  for(int e=t; e<CC*WW; e+=256){
    int w=e>>6, c=e&63; float v = tile[c][w];
    dst[e] = v;
    dstb[(w+1)*CC + c] = f2bf(v);
  }
  if(t<128){ int c=t&63; int side=t>>6; dstb[(size_t)side*129*CC + c] = 0; }
}

// ---------------- K4: offset conv, direct-global bf16 MFMA (no staging) ----------------
__global__ __launch_bounds__(256) void k_off(const ushort_t* __restrict__ outTbf,
  const ushort_t* __restrict__ offAbf, const float* __restrict__ offb,
  const float* __restrict__ obg, const float* __restrict__ obb,
  const float* __restrict__ obm, const float* __restrict__ obv,
  float* __restrict__ dyb)
{
  __shared__ float off_s[KSZ*128];
  int t = threadIdx.x;
  int wg = blockIdx.x; int sw = (wg&7)*64 + (wg>>3);   // XCD swizzle (512 % 8 == 0)
  int b = sw>>7, h = sw&127;
  int wid = t>>6, lane = t&63, arow = lane&15, kgrp = lane>>4;
  bf16x8 aFv[18];
  #pragma unroll
  for(int s=0;s<18;s++) aFv[s] = *(const bf16x8*)(offAbf + (s*16+arow)*32 + kgrp*8);
  f32x4 acc[2]; acc[0]=(f32x4){0.f,0.f,0.f,0.f}; acc[1]=(f32x4){0.f,0.f,0.f,0.f};
  #pragma unroll
  for(int s=0;s<18;s++){
    int tap = s>>1, chalf = s&1;
    int r = tap/3, dwp = tap%3;
    int hr = h - 1 + r;
    if(hr<0 || hr>=HH_) continue;     // wave-uniform; zero rows skipped exactly
    const ushort_t* base = outTbf + ((size_t)(b*HH_+hr))*130*CC + chalf*32 + kgrp*8;
    #pragma unroll
    for(int n2=0;n2<2;n2++){
      int wp = (wid*2+n2)*16 + arow + dwp;   // padded col index
      bf16x8 bF = *(const bf16x8*)(base + (size_t)wp*CC);
      acc[n2] = __builtin_amdgcn_mfma_f32_16x16x32_bf16(aFv[s], bF, acc[n2], 0,0,0);
    }
  }
  #pragma unroll
  for(int n2=0;n2<2;n2++){
    #pragma unroll
    for(int r=0;r<4;r++){
      int co = kgrp*4+r;
      if(co<KSZ) off_s[co*128 + (wid*2+n2)*16 + arow] = acc[n2][r];
    }
  }
  __syncthreads();
  if(t<128){
    int w = t;
    float y[KSZ];
    #pragma unroll
    for(int k=0;k<KSZ;k++){
      float sc = obg[k]*rsqrtf(obv[k]+EPSV);
      float sh = obb[k]-obm[k]*sc;
      y[k] = tanhf((off_s[k*128+w]+offb[k])*sc+sh);
    }
    float d0=y[0]+y[1]+y[2], d1=y[1]+y[2], d2=y[2];
    float d4=y[4], d5=y[4]+y[5], d6=y[4]+y[5]+y[6];
    size_t base = ((size_t)b*KSZ)*HPW + h*WW + w;
    dyb[base]=d0; dyb[base+HPW]=d1; dyb[base+2*HPW]=d2; dyb[base+3*HPW]=0.f;
    dyb[base+4*HPW]=d4; dyb[base+5*HPW]=d5; dyb[base+6*HPW]=d6;
  }
}

// ---------------- K5: dsconv v3 — 512 thr, K-chunked double-buffered MFMA GEMM ----------------
__global__ __launch_bounds__(512) void k_dsconv(const float* __restrict__ outT,
  const float* __restrict__ dyb, const ushort_t* __restrict__ dsWbf,
  const float* __restrict__ dsb, float* __restrict__ yout, float* __restrict__ pstats)
{
  __shared__ ushort_t S2[2][128*64];   // 2 x 16KB, 128B rows, XOR-swizzled
  __shared__ int sb0[KSZ][128], sb1[KSZ][128];
  __shared__ float swr[KSZ][128];
  int t = threadIdx.x;
  int wg = blockIdx.x; int sw = (wg&7)*64 + (wg>>3);   // XCD swizzle
  int b = sw>>7, h = sw&127;
  // sample meta for all 7x128 tasks
  for(int e=t; e<KSZ*128; e+=512){
    int k = e>>7, w = e&127;
    float dv = dyb[((size_t)(b*KSZ+k)*HH_ + h)*WW + w];
    float r = fminf(fmaxf((float)h + dv, 0.f), 127.f);
    float rf = floorf(r); int r0=(int)rf; float wr=r-rf; int r1=min(r0+1,127);
    int c = min(max(w+k-3,0),127);
    sb0[k][w] = ((b*HH_+r0)*WW+c)*CC;
    sb1[k][w] = ((b*HH_+r1)*WW+c)*CC;
    swr[k][w] = wr;
  }
  int wid = t>>6, lane = t&63, arow = lane&15, kgrp = lane>>4;
  int cg = wid&3, wh = wid>>2;     // co 16-group, w half
  __syncthreads();
  // fill chunk 0
  {
    ushort_t* buf = S2[0];
    #pragma unroll
    for(int i=0;i<16;i++){
      int p = (wid<<4)+i;
      int b0=sb0[0][p], b1=sb1[0][p]; float wr=swr[0][p];
      float a = outT[b0+lane], c2 = outT[b1+lane];
      float v = a + wr*(c2-a);
      int idx = (p<<6)|lane;
      buf[idx ^ ((p&7)<<3)] = f2bf(v);
    }
  }
  __syncthreads();
  f32x4 acc[4];
  #pragma unroll
  for(int nt=0;nt<4;nt++) acc[nt] = (f32x4){0.f,0.f,0.f,0.f};
  int buf = 0;
  for(int k=0;k<KSZ;k++){
    const ushort_t* Wp = dsWbf + (size_t)((cg<<4)+arow)*KTOT + (k<<6) + kgrp*8;
    bf16x8 a0 = *(const bf16x8*)Wp;
    bf16x8 a1 = *(const bf16x8*)(Wp+32);
    if(k+1<KSZ){  // prefetch next chunk into other buffer
      ushort_t* nb = S2[buf^1];
      #pragma unroll
      for(int i=0;i<16;i++){
        int p = (wid<<4)+i;
        int b0=sb0[k+1][p], b1=sb1[k+1][p]; float wr=swr[k+1][p];
        float a = outT[b0+lane], c2 = outT[b1+lane];
        float v = a + wr*(c2-a);
        int idx = (p<<6)|lane;
        nb[idx ^ ((p&7)<<3)] = f2bf(v);
      }
    }
    const ushort_t* cb = S2[buf];
    #pragma unroll
    for(int nt=0;nt<4;nt++){
      int pos = (wh<<6) + (nt<<4) + arow;
      int i0 = (pos<<6) + kgrp*8;
      int sz = (pos&7)<<3;
      bf16x8 b0 = *(const bf16x8*)(cb + (i0 ^ sz));
      bf16x8 b1 = *(const bf16x8*)(cb + ((i0+32) ^ sz));
      acc[nt] = __builtin_amdgcn_mfma_f32_16x16x32_bf16(a0, b0, acc[nt], 0,0,0);
      acc[nt] = __builtin_amdgcn_mfma_f32_16x16x32_bf16(a1, b1, acc[nt], 0,0,0);
    }
    __syncthreads();
    buf ^= 1;
  }
  // epilogue: write y + GN partials
  float vs[4]={0.f,0.f,0.f,0.f}, vq[4]={0.f,0.f,0.f,0.f};
  #pragma unroll
  for(int r=0;r<4;r++){
    int co = (cg<<4) + kgrp*4 + r;
    float bias = dsb[co];
    #pragma unroll
    for(int nt=0;nt<4;nt++){
      float y = acc[nt][r] + bias;
      int wcol = (wh<<6) + (nt<<4) + arow;
      yout[((size_t)(b*CC+co)*HH_ + h)*WW + wcol] = y;
      vs[r] += y; vq[r] += y*y;
    }
  }
  #pragma unroll
  for(int m=1;m<16;m<<=1){
    #pragma unroll
    for(int r=0;r<4;r++){ vs[r]+=__shfl_xor(vs[r],m); vq[r]+=__shfl_xor(vq[r],m); }
  }
  if(arow==0){
    #pragma unroll
    for(int r=0;r<4;r++){
      int co = (cg<<4)+kgrp*4+r;
      int pi = (b*CC+co)*256 + h*2 + wh;
      pstats[pi] = vs[r];
      pstats[65536+pi] = vq[r];
    }
  }
}

// ---------------- K6: reduce GN partials -> group stats ----------------
__global__ __launch_bounds__(256) void k_gnfin2(const float* __restrict__ pstats,
                                                float* __restrict__ gstat){
  int bg = blockIdx.x; int b = bg>>4, g = bg&15; int t = threadIdx.x;
  float s=0.f, q=0.f;
  #pragma unroll
  for(int c4=0;c4<4;c4++){
    int base = (b*CC + g*4+c4)*256;
    s += pstats[base + t];
    q += pstats[65536 + base + t];
  }
  for(int o=32;o>0;o>>=1){ s+=__shfl_down(s,o); q+=__shfl_down(q,o); }
  __shared__ float ls[4], lq[4];
  if((t&63)==0){ ls[t>>6]=s; lq[t>>6]=q; }
  __syncthreads();
  if(t==0){
    float S=ls[0]+ls[1]+ls[2]+ls[3], Q=lq[0]+lq[1]+lq[2]+lq[3];
    float inv = 1.0f/(4.0f*HPW);
    float mu = S*inv; float var = Q*inv - mu*mu;
    gstat[bg*2]=mu; gstat[bg*2+1]=rsqrtf(var+EPSV);
  }
}

// ---------------- K7: apply GN + affine + relu in place ----------------
__global__ void k_gnapply(float* __restrict__ y, const float* __restrict__ gstat,
  const float* __restrict__ gg, const float* __restrict__ gb){
  int idx = blockIdx.x*256 + threadIdx.x;
  float4* p = (float4*)y;
  int bc = idx >> 12;
  int b = bc>>6, c = bc&63;
  int gi = b*16 + (c>>2);
  float mu = gstat[gi*2], rstd = gstat[gi*2+1];
  float sc = rstd*gg[c], sh = gb[c]-mu*sc;
  float4 v = p[idx];
  v.x = fmaxf(v.x*sc+sh, 0.f);
  v.y = fmaxf(v.y*sc+sh, 0.f);
  v.z = fmaxf(v.z*sc+sh, 0.f);
  v.w = fmaxf(v.w*sc+sh, 0.f);
  p[idx] = v;
}

extern "C" void kernel_launch(void* const* d_in, const int* in_sizes, int n_in,
                              void* d_out, int out_size, void* d_ws, size_t ws_size,
                              hipStream_t stream) {
  const float* x      = (const float*)d_in[0];
  const float* weight = (const float*)d_in[1];
  const float* ratio  = (const float*)d_in[2];
  const float* o1fc   = (const float*)d_in[3];
  const float* o1g    = (const float*)d_in[4];
  const float* o1b    = (const float*)d_in[5];
  const float* o1m    = (const float*)d_in[6];
  const float* o1v    = (const float*)d_in[7];
  const float* o1cw   = (const float*)d_in[8];
  const float* o1cb   = (const float*)d_in[9];
  const float* o1fw   = (const float*)d_in[10];
  const float* o1fb   = (const float*)d_in[11];
  const float* o2fc   = (const float*)d_in[12];
  const float* o2g    = (const float*)d_in[13];
  const float* o2b    = (const float*)d_in[14];
  const float* o2m    = (const float*)d_in[15];
  const float* o2v    = (const float*)d_in[16];
  const float* o2cw   = (const float*)d_in[17];
  const float* o2cb   = (const float*)d_in[18];
  const float* o2fw   = (const float*)d_in[19];
  const float* o2fb   = (const float*)d_in[20];
  const float* spw    = (const float*)d_in[21];
  const float* spb    = (const float*)d_in[22];
  const float* offw   = (const float*)d_in[23];
  const float* offb   = (const float*)d_in[24];
  const float* obg    = (const float*)d_in[25];
  const float* obb    = (const float*)d_in[26];
  const float* obm    = (const float*)d_in[27];
  const float* obv    = (const float*)d_in[28];
  const float* dsw    = (const float*)d_in[29];
  const float* dsb    = (const float*)d_in[30];
  const float* gng    = (const float*)d_in[31];
  const float* gnb    = (const float*)d_in[32];

  float* ws    = (float*)d_ws;
  float* outT  = ws;                            // 4194304
  float* HHb   = ws + 4194304;                  // 1048576
  float* dyb   = ws + 5242880;                  // 458752 -> ends 5701632
  float* gbuf  = ws + 5701632;                  // 256
  float* weff  = ws + 5701888;                  // 2304 -> ends 5704192
  ushort_t* dsWbf  = (ushort_t*)(ws + 5704192); // 28672 shorts
  ushort_t* offAbf = (ushort_t*)(ws + 5718528); // 9216 shorts
  float* gstat = ws + 5723136;                  // 128
  float* attn  = ws + 5723264;                  // 1060
  float* pstats= ws + 5724416;                  // 131072 -> ends 5855488
  ushort_t* outTbf = (ushort_t*)(ws + 5855488); // 4*128*130*64 shorts = 8.5MB
  float* outb  = (float*)d_out;                 // NCHW scratch: out -> y -> final

  k_prep<<<148,256,0,stream>>>(dsw, offw, dsWbf, offAbf, gbuf);
  k_dwt_hh<<<4096,256,0,stream>>>(x, HHb, gbuf);
  k_att1<<<1,256,0,stream>>>(gbuf,
    o1fc,o1g,o1b,o1m,o1v,o1cw,o1cb,o1fw,o1fb,
    o2fc,o2g,o2b,o2m,o2v,o2cw,o2cb,o2fw,o2fb,
    spw,spb, attn);
  k_weff<<<256,64,0,stream>>>(weight, attn, ratio, weff);
  k_iwt<<<256,256,0,stream>>>(HHb, x, weff, outb);
  k_transpose<<<512,256,0,stream>>>(outb, outT, outTbf);
  k_off<<<512,256,0,stream>>>(outTbf, offAbf, offb, obg, obb, obm, obv, dyb);
  k_dsconv<<<512,512,0,stream>>>(outT, dyb, dsWbf, dsb, outb, pstats);
  k_gnfin2<<<64,256,0,stream>>>(pstats, gstat);
  k_gnapply<<<4096,256,0,stream>>>(outb, gstat, gng, gnb);
}

// Round 7
// 113.745 us; speedup vs baseline: 1.3394x; 1.0011x over previous
//
#include <hip/hip_runtime.h>
#include <math.h>

#define BB 4
#define CC 64
#define HH_ 128
#define WW 128
#define HPW (HH_*WW)     // 16384
#define KH 64
#define KW 64
#define KSZ 7
#define AA 16
#define EPSV 1e-5f
#define KTOT 448         // 7*64

typedef __attribute__((ext_vector_type(8))) short bf16x8;
typedef __attribute__((ext_vector_type(4))) float f32x4;
typedef unsigned short ushort_t;

__device__ __forceinline__ float sigm(float x){ return 1.0f/(1.0f+expf(-x)); }
__device__ __forceinline__ unsigned short f2bf(float f){
  unsigned u = __float_as_uint(f);
  return (unsigned short)((u + 0x7fffu + ((u>>16)&1u)) >> 16);
}

// ---------------- K0: prep (weight reformat, bf16 convert, gbuf zero) ----------------
__global__ void k_prep(const float* __restrict__ dsw, const float* __restrict__ offw,
                       ushort_t* __restrict__ dsWbf, ushort_t* __restrict__ offAbf,
                       float* __restrict__ gbuf){
  int idx = blockIdx.x*256 + threadIdx.x;
  if(blockIdx.x==0) gbuf[threadIdx.x] = 0.f;
  if(idx < CC*KTOT){
    int co = idx/KTOT; int K = idx%KTOT; int k = K>>6; int ci = K&63;
    dsWbf[idx] = f2bf(dsw[(size_t)(co*CC+ci)*KSZ + k]);
  } else {
    int j2 = idx - CC*KTOT;
    if(j2 < 18*16*32){
      int kl = j2&31; int co = (j2>>5)&15; int s = j2>>9;
      int tap = s>>1; int ci = (s&1)*32 + kl;
      float v = 0.f;
      if(co<KSZ) v = offw[((size_t)co*CC + ci)*9 + tap];
      offAbf[j2] = f2bf(v);
    }
  }
}

// ---------------- K1: HH from x + fused mean (atomic partials) ----------------
__global__ void k_dwt_hh(const float* __restrict__ x, float* __restrict__ HHb,
                         float* __restrict__ gbuf){
  int idx = blockIdx.x*256 + threadIdx.x;
  int w = idx & 63; int h = (idx>>6)&63; int bc = idx>>12;
  const float* xp = x + (size_t)bc*HPW;
  float2 r0 = *(const float2*)(xp + (2*h)*WW + 2*w);
  float2 r1 = *(const float2*)(xp + (2*h+1)*WW + 2*w);
  HHb[idx] = 0.5f*(r0.x - r1.x - r0.y + r1.y);
  float s = r0.x + r0.y + r1.x + r1.y;
  for(int o=32;o>0;o>>=1) s += __shfl_down(s,o);
  __shared__ float ls[4];
  int t = threadIdx.x;
  if((t&63)==0) ls[t>>6]=s;
  __syncthreads();
  if(t==0) atomicAdd(&gbuf[bc], ls[0]+ls[1]+ls[2]+ls[3]);
}

// ---------------- K2: fused attention + weff, grid (b,o), 64 thr ----------------
__global__ __launch_bounds__(64) void k_weff2(const float* __restrict__ g,
  const float* __restrict__ w, const float* __restrict__ ratio_p,
  const float* __restrict__ o1fc, const float* __restrict__ o1g,const float* __restrict__ o1b,
  const float* __restrict__ o1m,const float* __restrict__ o1v,
  const float* __restrict__ o1cw,const float* __restrict__ o1cb,
  const float* __restrict__ o1fw,const float* __restrict__ o1fb,
  const float* __restrict__ o2fc, const float* __restrict__ o2g,const float* __restrict__ o2b,
  const float* __restrict__ o2m,const float* __restrict__ o2v,
  const float* __restrict__ o2cw,const float* __restrict__ o2cb,
  const float* __restrict__ o2fw,const float* __restrict__ o2fb,
  const float* __restrict__ spw,const float* __restrict__ spb,
  float* __restrict__ weff)
{
  int bo = blockIdx.x; int b = bo>>6, o = bo&63; int ci = threadIdx.x;
  float g_own = g[b*CC+ci] * (1.0f/HPW);
  float d1=o1cb[ci], d2=o1fb[ci], d3=o2cb[ci], d4=o2fb[ci];
  float sspacc[9];
  #pragma unroll
  for(int e=0;e<9;e++) sspacc[e]=spb[e];
  for(int j=0;j<AA;j++){
    float p1 = g_own * o1fc[j*CC+ci];
    float p2 = g_own * o2fc[j*CC+ci];
    #pragma unroll
    for(int off=32;off>0;off>>=1){ p1+=__shfl_xor(p1,off); p2+=__shfl_xor(p2,off); }
    p1 = (p1-o1m[j])*rsqrtf(o1v[j]+EPSV)*o1g[j]+o1b[j]; p1=fmaxf(p1,0.f);
    p2 = (p2-o2m[j])*rsqrtf(o2v[j]+EPSV)*o2g[j]+o2b[j]; p2=fmaxf(p2,0.f);
    d1 += p1*o1cw[ci*AA+j]; d2 += p1*o1fw[ci*AA+j];
    d3 += p2*o2cw[ci*AA+j]; d4 += p2*o2fw[ci*AA+j];
    #pragma unroll
    for(int e=0;e<9;e++) sspacc[e] += p2*spw[e*AA+j];
  }
  float sc1v=sigm(d1), sc2v=sigm(d3);
  float sf1o=__shfl(sigm(d2),o), sf2o=__shfl(sigm(d4),o);
  const float* wp = w + (size_t)(o*CC+ci)*9;
  float w9[9]; float m=0.f;
  #pragma unroll
  for(int e=0;e<9;e++){ w9[e]=wp[e]; m+=w9[e]; }
  m *= (1.0f/9.0f);
  float S1 = m * sc1v;
  float M[9];
  #pragma unroll
  for(int e=0;e<9;e++) M[e] = (w9[e]-m)*sc2v;
  #pragma unroll
  for(int off=32; off>0; off>>=1){
    S1 += __shfl_xor(S1, off);
    #pragma unroll
    for(int e=0;e<9;e++) M[e] += __shfl_xor(M[e], off);
  }
  if(ci==0){
    const float Dm[3][3] = {{2.f,2.f,2.f},{1.7320508075688772f,0.f,-1.7320508075688772f},{1.f,-2.f,1.f}};
    const float Di[3][3] = {{0.16666666666666666f,0.28867513459481287f,0.16666666666666666f},
                            {0.16666666666666666f,0.f,-0.3333333333333333f},
                            {0.16666666666666666f,-0.28867513459481287f,0.16666666666666666f}};
    float U[3][3], T[3][3], V[3][3], R[3][3];
    for(int k=0;k<3;k++)for(int n=0;n<3;n++) U[k][n]=Dm[k][0]*M[0*3+n]+Dm[k][1]*M[1*3+n]+Dm[k][2]*M[2*3+n];
    for(int k=0;k<3;k++)for(int l=0;l<3;l++) T[k][l]=(U[k][0]*Dm[l][0]+U[k][1]*Dm[l][1]+U[k][2]*Dm[l][2])*2.0f*sigm(sspacc[k*3+l]);
    for(int k=0;k<3;k++)for(int n=0;n<3;n++) V[k][n]=Di[k][0]*T[0][n]+Di[k][1]*T[1][n]+Di[k][2]*T[2][n];
    for(int k=0;k<3;k++)for(int l=0;l<3;l++) R[k][l]=V[k][0]*Di[l][0]+V[k][1]*Di[l][1]+V[k][2]*Di[l][2];
    float rr = ratio_p[0];
    float base = rr*4.0f*sf1o*S1;
    float w2f = (1.0f-rr)*4.0f*sf2o;
    #pragma unroll
    for(int e=0;e<9;e++) weff[(size_t)bo*9+e] = base + w2f*R[e/3][e%3];
  }
}

// ---------------- K3: fused iwt + transpose -> outT f32 [b,h,w,c] + outTbf bf16 padded ----------------
__global__ __launch_bounds__(256) void k_iwtT(const float* __restrict__ HHb,
  const float* __restrict__ x, const float* __restrict__ weff,
  float* __restrict__ outT, ushort_t* __restrict__ outTbf)
{
  __shared__ float xt[CC][129];   // 33KB
  __shared__ float d_s[CC][65];   // 16.6KB
  int wg = blockIdx.x; int b = wg>>7, h = wg&127; int h2 = h>>1;
  int t = threadIdx.x;
  { // d = 0.5*(conv3x3(HH) - HH) at row h2
    int c = t>>2, q = t&3;
    float wk[9];
    #pragma unroll
    for(int e=0;e<9;e++) wk[e] = weff[(size_t)(b*CC+c)*9+e];
    const float* Hp = HHb + (size_t)(b*CC+c)*(KH*KW);
    #pragma unroll 4
    for(int j=0;j<16;j++){
      int w2 = q*16+j;
      float conv = 0.f;
      #pragma unroll
      for(int dh=-1;dh<=1;dh++){
        int r = h2+dh; if(r<0||r>=KH) continue;
        #pragma unroll
        for(int dw=-1;dw<=1;dw++){
          int wc2 = w2+dw; if(wc2<0||wc2>=KW) continue;
          conv += wk[(dh+1)*3+(dw+1)]*Hp[r*KW+wc2];
        }
      }
      d_s[c][w2] = 0.5f*(conv - Hp[h2*KW+w2]);
    }
  }
  // stage x row h (coalesced rows)
  for(int e=t; e<CC*WW; e+=256){
    int c=e>>7, w=e&127;
    xt[c][w] = x[((size_t)(b*CC+c)*HH_+h)*WW + w];
  }
  __syncthreads();
  float* dst = outT + ((size_t)(b*HH_+h))*WW*CC;
  ushort_t* dstb = outTbf + ((size_t)(b*HH_+h))*130*CC;
  for(int e=t; e<CC*WW; e+=256){
    int w=e>>6, c=e&63;
    float dv = d_s[c][w>>1];
    float val = 2.f*xt[c][w] + (((h + w)&1) ? -dv : dv);
    dst[e] = val;
    dstb[(w+1)*CC + c] = f2bf(val);
  }
  if(t<128){ int c=t&63; int side=t>>6; dstb[(size_t)side*129*CC + c] = 0; }
}

// ---------------- K4: fused offset-conv + dy + deform-sample GEMM + GN partials ----------------
__global__ __launch_bounds__(512) void k_dsfused(const float* __restrict__ outT,
  const ushort_t* __restrict__ outTbf, const ushort_t* __restrict__ dsWbf,
  const ushort_t* __restrict__ offAbf, const float* __restrict__ offb,
  const float* __restrict__ obg, const float* __restrict__ obb,
  const float* __restrict__ obm, const float* __restrict__ obv,
  const float* __restrict__ dsb, float* __restrict__ yout, float* __restrict__ pstats)
{
  __shared__ ushort_t S2[2][128*64];   // 32KB
  __shared__ int sb0[KSZ][128], sb1[KSZ][128];
  __shared__ float swr[KSZ][128];
  __shared__ float off_s[KSZ*128];
  __shared__ float dy_s[KSZ*128];
  int t = threadIdx.x;
  int wg = blockIdx.x; int sw = (wg&7)*64 + (wg>>3);   // XCD swizzle
  int b = sw>>7, h = sw&127;
  int wid = t>>6, lane = t&63, arow = lane&15, kgrp = lane>>4;
  // ---- Phase A: offset conv (waves 0-3), MFMA from padded bf16 global ----
  if(wid<4){
    f32x4 acc[2]; acc[0]=(f32x4){0.f,0.f,0.f,0.f}; acc[1]=(f32x4){0.f,0.f,0.f,0.f};
    #pragma unroll
    for(int s=0;s<18;s++){
      int tap = s>>1, chalf = s&1;
      int r = tap/3, dwp = tap%3;
      int hr = h - 1 + r;
      if(hr<0 || hr>=HH_) continue;
      bf16x8 aF = *(const bf16x8*)(offAbf + (s*16+arow)*32 + kgrp*8);
      const ushort_t* base = outTbf + ((size_t)(b*HH_+hr))*130*CC + chalf*32 + kgrp*8;
      #pragma unroll
      for(int n2=0;n2<2;n2++){
        int wp = (wid*2+n2)*16 + arow + dwp;
        bf16x8 bF = *(const bf16x8*)(base + (size_t)wp*CC);
        acc[n2] = __builtin_amdgcn_mfma_f32_16x16x32_bf16(aF, bF, acc[n2], 0,0,0);
      }
    }
    #pragma unroll
    for(int n2=0;n2<2;n2++){
      #pragma unroll
      for(int r=0;r<4;r++){
        int co = kgrp*4+r;
        if(co<KSZ) off_s[co*128 + (wid*2+n2)*16 + arow] = acc[n2][r];
      }
    }
  }
  __syncthreads();
  // ---- Phase B: BN + tanh + cumsum -> dy in LDS ----
  if(t<128){
    int w = t;
    float y[KSZ];
    #pragma unroll
    for(int k=0;k<KSZ;k++){
      float sc = obg[k]*rsqrtf(obv[k]+EPSV);
      float sh = obb[k]-obm[k]*sc;
      y[k] = tanhf((off_s[k*128+w]+offb[k])*sc+sh);
    }
    dy_s[      w]=y[0]+y[1]+y[2]; dy_s[128+w]=y[1]+y[2]; dy_s[256+w]=y[2];
    dy_s[384+w]=0.f; dy_s[512+w]=y[4]; dy_s[640+w]=y[4]+y[5]; dy_s[768+w]=y[4]+y[5]+y[6];
  }
  __syncthreads();
  // ---- Phase C: sample meta ----
  for(int e=t; e<KSZ*128; e+=512){
    int k = e>>7, w = e&127;
    float dv = dy_s[e];
    float r = fminf(fmaxf((float)h + dv, 0.f), 127.f);
    float rf = floorf(r); int r0=(int)rf; float wr=r-rf; int r1=min(r0+1,127);
    int c = min(max(w+k-3,0),127);
    sb0[k][w] = ((b*HH_+r0)*WW+c)*CC;
    sb1[k][w] = ((b*HH_+r1)*WW+c)*CC;
    swr[k][w] = wr;
  }
  __syncthreads();
  // ---- Phase D: K-chunked double-buffered sample + MFMA GEMM ----
  int cg = wid&3, wh = wid>>2;
  {
    ushort_t* buf = S2[0];
    #pragma unroll
    for(int i=0;i<16;i++){
      int p = (wid<<4)+i;
      int b0=sb0[0][p], b1=sb1[0][p]; float wr=swr[0][p];
      float a = outT[b0+lane], c2 = outT[b1+lane];
      float v = a + wr*(c2-a);
      int idx = (p<<6)|lane;
      buf[idx ^ ((p&7)<<3)] = f2bf(v);
    }
  }
  __syncthreads();
  f32x4 acc[4];
  #pragma unroll
  for(int nt=0;nt<4;nt++) acc[nt] = (f32x4){0.f,0.f,0.f,0.f};
  int buf = 0;
  for(int k=0;k<KSZ;k++){
    const ushort_t* Wp = dsWbf + (size_t)((cg<<4)+arow)*KTOT + (k<<6) + kgrp*8;
    bf16x8 a0 = *(const bf16x8*)Wp;
    bf16x8 a1 = *(const bf16x8*)(Wp+32);
    if(k+1<KSZ){
      ushort_t* nb = S2[buf^1];
      #pragma unroll
      for(int i=0;i<16;i++){
        int p = (wid<<4)+i;
        int b0=sb0[k+1][p], b1=sb1[k+1][p]; float wr=swr[k+1][p];
        float a = outT[b0+lane], c2 = outT[b1+lane];
        float v = a + wr*(c2-a);
        int idx = (p<<6)|lane;
        nb[idx ^ ((p&7)<<3)] = f2bf(v);
      }
    }
    const ushort_t* cb = S2[buf];
    #pragma unroll
    for(int nt=0;nt<4;nt++){
      int pos = (wh<<6) + (nt<<4) + arow;
      int i0 = (pos<<6) + kgrp*8;
      int sz = (pos&7)<<3;
      bf16x8 b0 = *(const bf16x8*)(cb + (i0 ^ sz));
      bf16x8 b1 = *(const bf16x8*)(cb + ((i0+32) ^ sz));
      acc[nt] = __builtin_amdgcn_mfma_f32_16x16x32_bf16(a0, b0, acc[nt], 0,0,0);
      acc[nt] = __builtin_amdgcn_mfma_f32_16x16x32_bf16(a1, b1, acc[nt], 0,0,0);
    }
    __syncthreads();
    buf ^= 1;
  }
  // ---- epilogue: y + GN partials ----
  float vs[4]={0.f,0.f,0.f,0.f}, vq[4]={0.f,0.f,0.f,0.f};
  #pragma unroll
  for(int r=0;r<4;r++){
    int co = (cg<<4) + kgrp*4 + r;
    float bias = dsb[co];
    #pragma unroll
    for(int nt=0;nt<4;nt++){
      float y = acc[nt][r] + bias;
      int wcol = (wh<<6) + (nt<<4) + arow;
      yout[((size_t)(b*CC+co)*HH_ + h)*WW + wcol] = y;
      vs[r] += y; vq[r] += y*y;
    }
  }
  #pragma unroll
  for(int m=1;m<16;m<<=1){
    #pragma unroll
    for(int r=0;r<4;r++){ vs[r]+=__shfl_xor(vs[r],m); vq[r]+=__shfl_xor(vq[r],m); }
  }
  if(arow==0){
    #pragma unroll
    for(int r=0;r<4;r++){
      int co = (cg<<4)+kgrp*4+r;
      int pi = (b*CC+co)*256 + h*2 + wh;
      pstats[pi] = vs[r];
      pstats[65536+pi] = vq[r];
    }
  }
}

// ---------------- K5: reduce GN partials -> group stats ----------------
__global__ __launch_bounds__(256) void k_gnfin2(const float* __restrict__ pstats,
                                                float* __restrict__ gstat){
  int bg = blockIdx.x; int b = bg>>4, g = bg&15; int t = threadIdx.x;
  float s=0.f, q=0.f;
  #pragma unroll
  for(int c4=0;c4<4;c4++){
    int base = (b*CC + g*4+c4)*256;
    s += pstats[base + t];
    q += pstats[65536 + base + t];
  }
  for(int o=32;o>0;o>>=1){ s+=__shfl_down(s,o); q+=__shfl_down(q,o); }
  __shared__ float ls[4], lq[4];
  if((t&63)==0){ ls[t>>6]=s; lq[t>>6]=q; }
  __syncthreads();
  if(t==0){
    float S=ls[0]+ls[1]+ls[2]+ls[3], Q=lq[0]+lq[1]+lq[2]+lq[3];
    float inv = 1.0f/(4.0f*HPW);
    float mu = S*inv; float var = Q*inv - mu*mu;
    gstat[bg*2]=mu; gstat[bg*2+1]=rsqrtf(var+EPSV);
  }
}

// ---------------- K6: apply GN + affine + relu in place ----------------
__global__ void k_gnapply(float* __restrict__ y, const float* __restrict__ gstat,
  const float* __restrict__ gg, const float* __restrict__ gb){
  int idx = blockIdx.x*256 + threadIdx.x;
  float4* p = (float4*)y;
  int bc = idx >> 12;
  int b = bc>>6, c = bc&63;
  int gi = b*16 + (c>>2);
  float mu = gstat[gi*2], rstd = gstat[gi*2+1];
  float sc = rstd*gg[c], sh = gb[c]-mu*sc;
  float4 v = p[idx];
  v.x = fmaxf(v.x*sc+sh, 0.f);
  v.y = fmaxf(v.y*sc+sh, 0.f);
  v.z = fmaxf(v.z*sc+sh, 0.f);
  v.w = fmaxf(v.w*sc+sh, 0.f);
  p[idx] = v;
}

extern "C" void kernel_launch(void* const* d_in, const int* in_sizes, int n_in,
                              void* d_out, int out_size, void* d_ws, size_t ws_size,
                              hipStream_t stream) {
  const float* x      = (const float*)d_in[0];
  const float* weight = (const float*)d_in[1];
  const float* ratio  = (const float*)d_in[2];
  const float* o1fc   = (const float*)d_in[3];
  const float* o1g    = (const float*)d_in[4];
  const float* o1b    = (const float*)d_in[5];
  const float* o1m    = (const float*)d_in[6];
  const float* o1v    = (const float*)d_in[7];
  const float* o1cw   = (const float*)d_in[8];
  const float* o1cb   = (const float*)d_in[9];
  const float* o1fw   = (const float*)d_in[10];
  const float* o1fb   = (const float*)d_in[11];
  const float* o2fc   = (const float*)d_in[12];
  const float* o2g    = (const float*)d_in[13];
  const float* o2b    = (const float*)d_in[14];
  const float* o2m    = (const float*)d_in[15];
  const float* o2v    = (const float*)d_in[16];
  const float* o2cw   = (const float*)d_in[17];
  const float* o2cb   = (const float*)d_in[18];
  const float* o2fw   = (const float*)d_in[19];
  const float* o2fb   = (const float*)d_in[20];
  const float* spw    = (const float*)d_in[21];
  const float* spb    = (const float*)d_in[22];
  const float* offw   = (const float*)d_in[23];
  const float* offb   = (const float*)d_in[24];
  const float* obg    = (const float*)d_in[25];
  const float* obb    = (const float*)d_in[26];
  const float* obm    = (const float*)d_in[27];
  const float* obv    = (const float*)d_in[28];
  const float* dsw    = (const float*)d_in[29];
  const float* dsb    = (const float*)d_in[30];
  const float* gng    = (const float*)d_in[31];
  const float* gnb    = (const float*)d_in[32];

  float* ws    = (float*)d_ws;
  float* HHb   = ws;                            // 1048576
  float* gbuf  = ws + 1048576;                  // 256
  float* weff  = ws + 1048832;                  // 2304
  ushort_t* dsWbf  = (ushort_t*)(ws + 1051136); // 28672 shorts
  ushort_t* offAbf = (ushort_t*)(ws + 1065472); // 9216 shorts
  float* gstat = ws + 1070080;                  // 128
  float* pstats= ws + 1070208;                  // 131072
  float* outT  = ws + 1201280;                  // 4194304 (f32 [b,h,w,c])
  ushort_t* outTbf = (ushort_t*)(ws + 5395584); // 4*128*130*64 shorts (padded)
  float* outb  = (float*)d_out;                 // y then final

  k_prep<<<148,256,0,stream>>>(dsw, offw, dsWbf, offAbf, gbuf);
  k_dwt_hh<<<4096,256,0,stream>>>(x, HHb, gbuf);
  k_weff2<<<256,64,0,stream>>>(gbuf, weight, ratio,
    o1fc,o1g,o1b,o1m,o1v,o1cw,o1cb,o1fw,o1fb,
    o2fc,o2g,o2b,o2m,o2v,o2cw,o2cb,o2fw,o2fb,
    spw,spb, weff);
  k_iwtT<<<512,256,0,stream>>>(HHb, x, weff, outT, outTbf);
  k_dsfused<<<512,512,0,stream>>>(outT, outTbf, dsWbf, offAbf,
    offb, obg, obb, obm, obv, dsb, outb, pstats);
  k_gnfin2<<<64,256,0,stream>>>(pstats, gstat);
  k_gnapply<<<4096,256,0,stream>>>(outb, gstat, gng, gnb);
}